// Round 12
// baseline (239.632 us; speedup 1.0000x reference)
//
#include <hip/hip_runtime.h>
#include <hip/hip_bf16.h>

// B=2, C=512, H=W=64 -> N=4096, 32 groups of 16 channels
#define BATCH 2
#define CDIM 512
#define NDIM 4096
#define NGROUPS 32
#define CHPG 16
#define GN_EPS 1e-6f

typedef __attribute__((ext_vector_type(8))) short bf16x8;   // 8 bf16 = 4 VGPRs
typedef __attribute__((ext_vector_type(4))) float f32x4;

__device__ __forceinline__ void gl_lds16(const void* g, void* lds) {
  __builtin_amdgcn_global_load_lds((__attribute__((address_space(1))) void*)(g),
                                   (__attribute__((address_space(3))) void*)(lds), 16, 0, 0);
}

template <int N>
__device__ __forceinline__ void wait_vmcnt() {
  if constexpr (N == 1) asm volatile("s_waitcnt vmcnt(1)" ::: "memory");
  else if constexpr (N == 2) asm volatile("s_waitcnt vmcnt(2)" ::: "memory");
  else if constexpr (N == 3) asm volatile("s_waitcnt vmcnt(3)" ::: "memory");
  else if constexpr (N == 4) asm volatile("s_waitcnt vmcnt(4)" ::: "memory");
  else if constexpr (N == 5) asm volatile("s_waitcnt vmcnt(5)" ::: "memory");
  else if constexpr (N == 6) asm volatile("s_waitcnt vmcnt(6)" ::: "memory");
  else asm volatile("s_waitcnt vmcnt(8)" ::: "memory");
}

__device__ __forceinline__ void raw_barrier() {
  asm volatile("s_barrier" ::: "memory");
}

__device__ __forceinline__ void drain_vm() {
  asm volatile("s_waitcnt vmcnt(0)" ::: "memory");
}

__device__ __forceinline__ short bf16_bits(float v) {
  __hip_bfloat16 h = __float2bfloat16(v);
  union { __hip_bfloat16 h; short s; } u;
  u.h = h;
  return u.s;
}

// ---------------- GroupNorm stats, two-stage ----------------
__global__ __launch_bounds__(256) void gn_stats_p1(const float* __restrict__ x,
                                                   float2* __restrict__ part) {
  int blk = blockIdx.x;
  int chunk = blk & 15, bg = blk >> 4;
  const float4* p = (const float4*)(x + (size_t)bg * (CHPG * NDIM) + chunk * 4096);
  float s = 0.f, ss = 0.f;
#pragma unroll
  for (int t = 0; t < 4; t++) {
    float4 v = p[threadIdx.x + t * 256];
    s += v.x + v.y + v.z + v.w;
    ss += v.x * v.x + v.y * v.y + v.z * v.z + v.w * v.w;
  }
  int w = threadIdx.x >> 6, l = threadIdx.x & 63;
#pragma unroll
  for (int off = 32; off > 0; off >>= 1) {
    s += __shfl_down(s, off);
    ss += __shfl_down(ss, off);
  }
  __shared__ float r1[4], r2[4];
  if (l == 0) { r1[w] = s; r2[w] = ss; }
  __syncthreads();
  if (threadIdx.x == 0)
    part[blk] = make_float2(r1[0] + r1[1] + r1[2] + r1[3], r2[0] + r2[1] + r2[2] + r2[3]);
}

__global__ __launch_bounds__(64) void gn_stats_p2(const float2* __restrict__ part,
                                                  float2* __restrict__ stats) {
  int bg = threadIdx.x;  // 64
  float s = 0.f, ss = 0.f;
#pragma unroll
  for (int c = 0; c < 16; c++) {
    float2 v = part[bg * 16 + c];
    s += v.x; ss += v.y;
  }
  const float inv = 1.0f / (CHPG * NDIM);
  float mean = s * inv;
  float var = ss * inv - mean * mean;
  stats[bg] = make_float2(mean, rsqrtf(var + GN_EPS));
}

// ------ GroupNorm apply + transpose to channel-last bf16: h_t[b][n][c] ------
__global__ __launch_bounds__(256) void gn_apply_t(const float* __restrict__ x,
                                                  const float2* __restrict__ stats,
                                                  const float* __restrict__ w,
                                                  const float* __restrict__ bias,
                                                  __hip_bfloat16* __restrict__ ht) {
  __shared__ __hip_bfloat16 tile[64][66];
  int b = blockIdx.z, c0 = blockIdx.y * 64, n0 = blockIdx.x * 64;
  int tq = threadIdx.x >> 6;
  int tl = threadIdx.x & 63;
#pragma unroll
  for (int i = 0; i < 16; i++) {
    int cl = tq * 16 + i;
    int c = c0 + cl;
    float2 st = stats[b * NGROUPS + (c >> 4)];
    float v = x[((size_t)b * CDIM + c) * NDIM + n0 + tl];
    v = (v - st.x) * st.y * w[c] + bias[c];
    tile[tl][cl] = __float2bfloat16(v);
  }
  __syncthreads();
#pragma unroll
  for (int i = 0; i < 16; i++) {
    int nl = tq * 16 + i;
    ht[((size_t)b * NDIM + n0 + nl) * CDIM + c0 + tl] = tile[nl][tl];
  }
}

// --- fp32 -> bf16 weights; also concat [bq;bk] bias into bqk (block 0) ---
__global__ __launch_bounds__(256) void cvt_w(const float* __restrict__ a, const float* __restrict__ b,
                                             const float* __restrict__ c, const float* __restrict__ d,
                                             __hip_bfloat16* __restrict__ o,
                                             const float* __restrict__ bq, const float* __restrict__ bk,
                                             float* __restrict__ bqk) {
  int i = blockIdx.x * 256 + threadIdx.x;
  o[i]          = __float2bfloat16(a[i]);
  o[i + 262144] = __float2bfloat16(b[i]);
  o[i + 524288] = __float2bfloat16(c[i]);
  o[i + 786432] = __float2bfloat16(d[i]);
  if (blockIdx.x == 0) {
#pragma unroll
    for (int t = 0; t < 4; t++) {
      int j = threadIdx.x + t * 256;  // 0..1023
      bqk[j] = (j < 512) ? bq[j] : bk[j - 512];
    }
  }
}

// ---------------- MFMA NT GEMM, pipelined + LDS-swizzled ----------------
// C[m][n] = scale * sum_k A[m][k]*B[n][k]  (+bias) (+res)
// A: [M x K] bf16 row stride lda; B: [N x K] bf16 row stride ldb; C stride ldc.
// BK = 32*KU, 4 waves (2x2), wave tile (MT/2)x(NT/2).
// K-loop: dbuf LDS, prefetch t+1, vmcnt(NL), raw barriers; staging column
// swizzle keeps fragment ds_read_b128 conflict-free.
// Epilogue: LDS repack -> coalesced 16B stores, or DIRECT scalar stores when
// the repack buffer would exceed 64 KB (large-tile bf16 path — repack was
// measured perf-neutral in r10).
// EXPZ: value=exp(value); per-(half-tile) row sums -> zsum_g[b][bx*2+wx][m]
//       (32 partials with grid.x=16). SCALEM: value *= cinv_g[b][m].
// OUT_MODE: 0 f32, 1 bf16. BIAS_MODE: 0 none, 1 bias[m], 2 bias[n].
// SWIZ (grid (GX,32,z)): co-locate A-sharing blocks on one XCD.
template <int MT, int NT, int KU, int BIAS_MODE, bool HAS_RES, int OUT_MODE,
          bool EXPZ, bool SCALEM, bool SWIZ, int MINB>
__global__ __launch_bounds__(256, MINB) void mfma_gemm_nt(
    const __hip_bfloat16* __restrict__ A, const __hip_bfloat16* __restrict__ B,
    const float* __restrict__ bias, const float* __restrict__ res,
    void* __restrict__ Cout, float* __restrict__ zsum_g, const float* __restrict__ cinv_g,
    int M, int N, int K, long sA, long sB, long sC,
    long lda, long ldb, long ldc, float scale) {
  constexpr int MTI = MT / 32, NTI = NT / 32;   // 16x16 acc tiles per wave
  constexpr int SB = 64 * KU;                   // bytes per row k-slab
  constexpr int ABYT = MT * SB, BBYT = NT * SB;
  constexpr int BUFB = ABYT + BBYT;
  constexpr int AISS = MT * KU / 64, BISS = NT * KU / 64;
  constexpr int NL = AISS + BISS;
  constexpr int RPI = 16 / KU;                  // rows per staging issue
  constexpr int ES = (OUT_MODE == 0) ? 4 : 2;   // out element size
  constexpr int RS = NT * ES + 16;              // repack row stride (pad = 16B)
  constexpr int REPB = MT * RS;
  constexpr bool DIRECT = (REPB > 65536);       // skip repack for huge tiles
  constexpr int SMEMB = DIRECT ? (2 * BUFB) : ((2 * BUFB > REPB) ? 2 * BUFB : REPB);
  constexpr int CPR = NT * ES / 16;             // 16B chunks per row
  constexpr int NCH = MT * CPR / 256;           // chunks per thread
  __shared__ char smem[SMEMB];
  const int tid = threadIdx.x;
  const int w = tid >> 6, l = tid & 63;
  const int wy = w >> 1, wx = w & 1;
  const int bz = blockIdx.z;
  int bx = blockIdx.x, by = blockIdx.y;
  if constexpr (SWIZ) {
    int l2 = by * gridDim.x + bx;
    int xcd = l2 & 7, s = l2 >> 3;
    by = xcd + (s & 3) * 8;
    bx = s >> 2;
  }
  const int m0 = by * MT, n0 = bx * NT;
  f32x4 acc[MTI][NTI] = {};

  // staging source column swizzle (bytes within the SB row-slab)
  int so;
  if constexpr (KU == 1) so = (((l & 3) - (l >> 2) - (l >> 4)) & 3) * 16;
  else                   so = (((l & 7) - (l >> 3)) & 7) * 16;
  const int lrow = (KU == 1) ? (l >> 2) : (l >> 3);
  const int arow = w * (MT / 4) + lrow;
  const int brow = w * (NT / 4) + lrow;
  const char* Ag = (const char*)A + ((size_t)bz * sA + (size_t)(m0 + arow) * lda) * 2 + so;
  const char* Bg = (const char*)B + ((size_t)bz * sB + (size_t)(n0 + brow) * ldb) * 2 + so;
  const size_t iadvA = (size_t)RPI * lda * 2;
  const size_t iadvB = (size_t)RPI * ldb * 2;
  const int woffA = w * (MT / 4) * SB;
  const int woffB = ABYT + w * (NT / 4) * SB;

  auto issue = [&](int buf) {
    char* base = smem + buf * BUFB;
#pragma unroll
    for (int i = 0; i < AISS; i++) gl_lds16(Ag + i * iadvA, base + woffA + i * 1024);
#pragma unroll
    for (int i = 0; i < BISS; i++) gl_lds16(Bg + i * iadvB, base + woffB + i * 1024);
    Ag += SB; Bg += SB;
  };

  // fragment-read column offsets (per KU half)
  const int x = l & 15;
  int qr0, qr1 = 0;
  if constexpr (KU == 1) {
    qr0 = (((l >> 4) + x + (x >> 2)) & 3) * 16;
  } else {
    qr0 = (((l >> 4) + (l & 7)) & 7) * 16;
    qr1 = (((l >> 4) + 4 + (l & 7)) & 7) * 16;
  }

  issue(0);
  const int T = K / (32 * KU);
  for (int t = 0; t < T; t++) {
    issue((t + 1) & 1);       // prefetch t+1 (last iter overshoots <=SB, lands in ws)
    wait_vmcnt<NL>();
    raw_barrier();
    const char* Asb = smem + (t & 1) * BUFB;
    const char* Bsb = Asb + ABYT;
#pragma unroll
    for (int h = 0; h < KU; h++) {
      const int q = (h == 0) ? qr0 : qr1;
      bf16x8 af[MTI], bfr[NTI];
#pragma unroll
      for (int mt = 0; mt < MTI; mt++)
        af[mt] = *(const bf16x8*)(Asb + (wy * (MT / 2) + mt * 16 + x) * SB + q);
#pragma unroll
      for (int nt = 0; nt < NTI; nt++)
        bfr[nt] = *(const bf16x8*)(Bsb + (wx * (NT / 2) + nt * 16 + x) * SB + q);
#pragma unroll
      for (int mt = 0; mt < MTI; mt++)
#pragma unroll
        for (int nt = 0; nt < NTI; nt++)
          acc[mt][nt] = __builtin_amdgcn_mfma_f32_16x16x32_bf16(af[mt], bfr[nt], acc[mt][nt], 0, 0, 0);
    }
    raw_barrier();            // all waves done reading buf before t+2 overwrites
  }

  // ---- epilogue ----
  drain_vm();      // stray tile-T prefetch landed
  raw_barrier();
  const size_t cbase = (size_t)bz * sC;
#pragma unroll
  for (int mt = 0; mt < MTI; mt++) {
#pragma unroll
    for (int r = 0; r < 4; r++) {
      const int row = wy * (MT / 2) + mt * 16 + (l >> 4) * 4 + r;  // block-local m
      float bvm = (BIAS_MODE == 1) ? bias[m0 + row] : 0.f;
      float cm = 1.f;
      if constexpr (SCALEM) cm = cinv_g[(size_t)bz * M + m0 + row];
      float z = 0.f;
#pragma unroll
      for (int nt = 0; nt < NTI; nt++) {
        const int nl = wx * (NT / 2) + nt * 16 + x;
        float v = acc[mt][nt][r] * scale + bvm;
        if (BIAS_MODE == 2) v += bias[n0 + nl];
        if constexpr (EXPZ) { v = __expf(v); z += v; }
        if constexpr (SCALEM) v *= cm;
        if constexpr (DIRECT) {
          ((__hip_bfloat16*)Cout)[cbase + (size_t)(m0 + row) * ldc + n0 + nl] = __float2bfloat16(v);
        } else {
          if (OUT_MODE == 0) *(float*)(smem + row * RS + nl * 4) = v;
          else *(short*)(smem + row * RS + nl * 2) = bf16_bits(v);
        }
      }
      if constexpr (EXPZ) {
        z += __shfl_xor(z, 1); z += __shfl_xor(z, 2);
        z += __shfl_xor(z, 4); z += __shfl_xor(z, 8);
        if (x == 0)
          zsum_g[((size_t)bz * 32 + bx * 2 + wx) * M + m0 + row] = z;
      }
    }
  }
  if constexpr (!DIRECT) {
    __syncthreads();
#pragma unroll
    for (int i = 0; i < NCH; i++) {
      const int g = i * 256 + tid;
      const int row = g / CPR;
      const int off = (g % CPR) * 16;
      char* dst = (char*)Cout + (cbase + (size_t)(m0 + row) * ldc + n0) * ES + off;
      if (OUT_MODE == 0) {
        float4 d = *(float4*)(smem + row * RS + off);
        if constexpr (HAS_RES) {
          float4 rv = *(const float4*)((const char*)res + (cbase + (size_t)(m0 + row) * ldc + n0) * 4 + off);
          d.x += rv.x; d.y += rv.y; d.z += rv.z; d.w += rv.w;
        }
        *(float4*)dst = d;
      } else {
        int4 d = *(int4*)(smem + row * RS + off);
        *(int4*)dst = d;
      }
    }
  }
}

// ---------------- Z combine: cinv[b][j] = 1 / sum_p zsum[b][p][j] ----------------
__global__ __launch_bounds__(256) void zcomb(const float* __restrict__ zsum,
                                             float* __restrict__ cinv) {
  int idx = blockIdx.x * 256 + threadIdx.x;  // b*NDIM + j, 8192 total
  int b = idx >> 12, j = idx & (NDIM - 1);
  float s = 0.f;
#pragma unroll 8
  for (int p = 0; p < 32; p++) s += zsum[((size_t)b * 32 + p) * NDIM + j];
  cinv[idx] = 1.0f / s;
}

extern "C" void kernel_launch(void* const* d_in, const int* in_sizes, int n_in,
                              void* d_out, int out_size, void* d_ws, size_t ws_size,
                              hipStream_t stream) {
  const float* x      = (const float*)d_in[0];
  const float* norm_w = (const float*)d_in[1];
  const float* norm_b = (const float*)d_in[2];
  const float* wq = (const float*)d_in[3];
  const float* bq = (const float*)d_in[4];
  const float* wk = (const float*)d_in[5];
  const float* bk = (const float*)d_in[6];
  const float* wv = (const float*)d_in[7];
  const float* bv = (const float*)d_in[8];
  const float* wp = (const float*)d_in[9];
  const float* bp = (const float*)d_in[10];
  float* out = (float*)d_out;

  const long CN = (long)CDIM * NDIM;       // 2M elems
  const long NN = (long)NDIM * NDIM;       // 16M elems
  const long QKN = (long)NDIM * 1024;      // merged q|k, [N,1024]
  char* p = (char*)d_ws;
  auto carve = [&](size_t bytes) { char* r = p; p += (bytes + 255) & ~(size_t)255; return r; };
  __hip_bfloat16* h_t  = (__hip_bfloat16*)carve(BATCH * CN * 2);   // [B,N,C]
  __hip_bfloat16* wb   = (__hip_bfloat16*)carve(4 * 512 * 512 * 2);
  __hip_bfloat16* qk_t = (__hip_bfloat16*)carve(BATCH * QKN * 2);  // [B,N,1024]: q 0-511, k 512-1023
  __hip_bfloat16* vb   = (__hip_bfloat16*)carve(BATCH * CN * 2);   // [B,C,N]
  __hip_bfloat16* ht2  = (__hip_bfloat16*)carve(BATCH * CN * 2);   // [B,N,C]
  __hip_bfloat16* St   = (__hip_bfloat16*)carve(BATCH * NN * 2);   // [B,N,N] E^T = exp(S^T)
  float* zsum  = (float*)carve((size_t)BATCH * 64 * NDIM * 4);     // slack for stray prefetch
  float* cinv  = (float*)carve(BATCH * NDIM * 4);
  float* bqk   = (float*)carve(1024 * 4);
  float2* stats = (float2*)carve(BATCH * NGROUPS * sizeof(float2));
  float2* gnpart = (float2*)carve(1024 * sizeof(float2));
  __hip_bfloat16* wbv = wb + 524288;
  __hip_bfloat16* wbp = wb + 786432;

  const float scale = 0.044194173824159216f;  // 512^-0.5

  gn_stats_p1<<<dim3(1024), 256, 0, stream>>>(x, gnpart);
  gn_stats_p2<<<dim3(1), 64, 0, stream>>>(gnpart, stats);
  gn_apply_t<<<dim3(NDIM / 64, CDIM / 64, BATCH), 256, 0, stream>>>(x, stats, norm_w, norm_b, h_t);
  cvt_w<<<dim3(1024), 256, 0, stream>>>(wq, wk, wv, wp, wb, bq, bk, bqk);

  // qk_t[n][0..1023] = h_t @ [wq;wk]^T + [bq;bk]   (SWIZ; BK=64)
  mfma_gemm_nt<128, 64, 2, 2, false, 1, false, false, true, 3><<<dim3(16, 32, BATCH), 256, 0, stream>>>(
      h_t, wb, bqk, nullptr, qk_t, nullptr, nullptr,
      NDIM, 1024, CDIM, CN, 0, QKN, CDIM, CDIM, 1024, 1.0f);
  // v = wv @ h_t^T + bv -> [C, N]   (BK=64)
  mfma_gemm_nt<64, 128, 2, 1, false, 1, false, false, false, 2><<<dim3(32, 8, BATCH), 256, 0, stream>>>(
      wbv, h_t, bv, nullptr, vb, nullptr, nullptr,
      CDIM, NDIM, CDIM, 0, CN, CN, CDIM, CDIM, NDIM, 1.0f);
  // E^T = exp(k_t @ q_t^T * scale) -> [N, N] bf16, fused partial Z row-sums
  // 256x256 block (wave 128x128): halves LDS bytes/MFMA (the measured limiter)
  mfma_gemm_nt<256, 256, 1, 0, false, 1, true, false, false, 1><<<dim3(16, 16, BATCH), 256, 0, stream>>>(
      qk_t + 512, qk_t, nullptr, nullptr, St, zsum, nullptr,
      NDIM, NDIM, CDIM, QKN, QKN, NN, 1024, 1024, NDIM, scale);
  zcomb<<<dim3(32), 256, 0, stream>>>(zsum, cinv);
  // ht2 = diag(cinv) (E^T @ v^T) -> [N, C]   (SWIZ; BK=64)
  mfma_gemm_nt<128, 64, 2, 0, false, 1, false, true, true, 2><<<dim3(8, 32, BATCH), 256, 0, stream>>>(
      St, vb, nullptr, nullptr, ht2, nullptr, cinv,
      NDIM, CDIM, NDIM, NN, CN, CN, NDIM, NDIM, CDIM, 1.0f);
  // out = wp @ ht2^T + bp + x -> [C, N] fp32 (residual fused in store phase)
  mfma_gemm_nt<64, 128, 2, 1, true, 0, false, false, false, 2><<<dim3(32, 8, BATCH), 256, 0, stream>>>(
      wbp, ht2, bp, x, out, nullptr, nullptr,
      CDIM, NDIM, CDIM, 0, CN, CN, CDIM, CDIM, NDIM, 1.0f);
}

// Round 13
// 229.578 us; speedup vs baseline: 1.0438x; 1.0438x over previous
//
#include <hip/hip_runtime.h>
#include <hip/hip_bf16.h>

// B=2, C=512, H=W=64 -> N=4096, 32 groups of 16 channels
#define BATCH 2
#define CDIM 512
#define NDIM 4096
#define NGROUPS 32
#define CHPG 16
#define GN_EPS 1e-6f

typedef __attribute__((ext_vector_type(8))) short bf16x8;   // 8 bf16 = 4 VGPRs
typedef __attribute__((ext_vector_type(4))) float f32x4;

__device__ __forceinline__ void gl_lds16(const void* g, void* lds) {
  __builtin_amdgcn_global_load_lds((__attribute__((address_space(1))) void*)(g),
                                   (__attribute__((address_space(3))) void*)(lds), 16, 0, 0);
}

template <int N>
__device__ __forceinline__ void wait_vmcnt() {
  if constexpr (N == 1) asm volatile("s_waitcnt vmcnt(1)" ::: "memory");
  else if constexpr (N == 2) asm volatile("s_waitcnt vmcnt(2)" ::: "memory");
  else if constexpr (N == 3) asm volatile("s_waitcnt vmcnt(3)" ::: "memory");
  else if constexpr (N == 4) asm volatile("s_waitcnt vmcnt(4)" ::: "memory");
  else if constexpr (N == 5) asm volatile("s_waitcnt vmcnt(5)" ::: "memory");
  else if constexpr (N == 6) asm volatile("s_waitcnt vmcnt(6)" ::: "memory");
  else asm volatile("s_waitcnt vmcnt(8)" ::: "memory");
}

__device__ __forceinline__ void raw_barrier() {
  asm volatile("s_barrier" ::: "memory");
}

__device__ __forceinline__ void drain_vm() {
  asm volatile("s_waitcnt vmcnt(0)" ::: "memory");
}

__device__ __forceinline__ short bf16_bits(float v) {
  __hip_bfloat16 h = __float2bfloat16(v);
  union { __hip_bfloat16 h; short s; } u;
  u.h = h;
  return u.s;
}

// ---------------- GroupNorm stats, two-stage ----------------
__global__ __launch_bounds__(256) void gn_stats_p1(const float* __restrict__ x,
                                                   float2* __restrict__ part) {
  int blk = blockIdx.x;
  int chunk = blk & 15, bg = blk >> 4;
  const float4* p = (const float4*)(x + (size_t)bg * (CHPG * NDIM) + chunk * 4096);
  float s = 0.f, ss = 0.f;
#pragma unroll
  for (int t = 0; t < 4; t++) {
    float4 v = p[threadIdx.x + t * 256];
    s += v.x + v.y + v.z + v.w;
    ss += v.x * v.x + v.y * v.y + v.z * v.z + v.w * v.w;
  }
  int w = threadIdx.x >> 6, l = threadIdx.x & 63;
#pragma unroll
  for (int off = 32; off > 0; off >>= 1) {
    s += __shfl_down(s, off);
    ss += __shfl_down(ss, off);
  }
  __shared__ float r1[4], r2[4];
  if (l == 0) { r1[w] = s; r2[w] = ss; }
  __syncthreads();
  if (threadIdx.x == 0)
    part[blk] = make_float2(r1[0] + r1[1] + r1[2] + r1[3], r2[0] + r2[1] + r2[2] + r2[3]);
}

__global__ __launch_bounds__(64) void gn_stats_p2(const float2* __restrict__ part,
                                                  float2* __restrict__ stats) {
  int bg = threadIdx.x;  // 64
  float s = 0.f, ss = 0.f;
#pragma unroll
  for (int c = 0; c < 16; c++) {
    float2 v = part[bg * 16 + c];
    s += v.x; ss += v.y;
  }
  const float inv = 1.0f / (CHPG * NDIM);
  float mean = s * inv;
  float var = ss * inv - mean * mean;
  stats[bg] = make_float2(mean, rsqrtf(var + GN_EPS));
}

// ------ GroupNorm apply + transpose to channel-last bf16: h_t[b][n][c] ------
__global__ __launch_bounds__(256) void gn_apply_t(const float* __restrict__ x,
                                                  const float2* __restrict__ stats,
                                                  const float* __restrict__ w,
                                                  const float* __restrict__ bias,
                                                  __hip_bfloat16* __restrict__ ht) {
  __shared__ __hip_bfloat16 tile[64][66];
  int b = blockIdx.z, c0 = blockIdx.y * 64, n0 = blockIdx.x * 64;
  int tq = threadIdx.x >> 6;
  int tl = threadIdx.x & 63;
#pragma unroll
  for (int i = 0; i < 16; i++) {
    int cl = tq * 16 + i;
    int c = c0 + cl;
    float2 st = stats[b * NGROUPS + (c >> 4)];
    float v = x[((size_t)b * CDIM + c) * NDIM + n0 + tl];
    v = (v - st.x) * st.y * w[c] + bias[c];
    tile[tl][cl] = __float2bfloat16(v);
  }
  __syncthreads();
#pragma unroll
  for (int i = 0; i < 16; i++) {
    int nl = tq * 16 + i;
    ht[((size_t)b * NDIM + n0 + nl) * CDIM + c0 + tl] = tile[nl][tl];
  }
}

// --- fp32 -> bf16 weights; also concat [bq;bk] bias into bqk (block 0) ---
__global__ __launch_bounds__(256) void cvt_w(const float* __restrict__ a, const float* __restrict__ b,
                                             const float* __restrict__ c, const float* __restrict__ d,
                                             __hip_bfloat16* __restrict__ o,
                                             const float* __restrict__ bq, const float* __restrict__ bk,
                                             float* __restrict__ bqk) {
  int i = blockIdx.x * 256 + threadIdx.x;
  o[i]          = __float2bfloat16(a[i]);
  o[i + 262144] = __float2bfloat16(b[i]);
  o[i + 524288] = __float2bfloat16(c[i]);
  o[i + 786432] = __float2bfloat16(d[i]);
  if (blockIdx.x == 0) {
#pragma unroll
    for (int t = 0; t < 4; t++) {
      int j = threadIdx.x + t * 256;  // 0..1023
      bqk[j] = (j < 512) ? bq[j] : bk[j - 512];
    }
  }
}

// ---------------- MFMA NT GEMM, pipelined + LDS-swizzled ----------------
// C[m][n] = scale * sum_k A[m][k]*B[n][k]  (+bias) (+res)
// A: [M x K] bf16 row stride lda; B: [N x K] bf16 row stride ldb; C stride ldc.
// BK = 32*KU, 4 waves (2x2), wave tile (MT/2)x(NT/2).
// K-loop: dbuf LDS, prefetch t+1, vmcnt(NL), raw barriers; staging column
// swizzle keeps fragment ds_read_b128 conflict-free.
// Epilogue: LDS repack -> coalesced 16B stores.
// EXPZ: value=exp(value); per-(half-tile) row sums -> zsum_g[b][bx*2+wx][m]
//       (64 partials with grid.x=32). SCALEM: value *= cinv_g[b][m].
// OUT_MODE: 0 f32, 1 bf16. BIAS_MODE: 0 none, 1 bias[m], 2 bias[n].
// SWIZ (grid (GX,32,z)): co-locate A-sharing blocks on one XCD.
template <int MT, int NT, int KU, int BIAS_MODE, bool HAS_RES, int OUT_MODE,
          bool EXPZ, bool SCALEM, bool SWIZ, int MINB>
__global__ __launch_bounds__(256, MINB) void mfma_gemm_nt(
    const __hip_bfloat16* __restrict__ A, const __hip_bfloat16* __restrict__ B,
    const float* __restrict__ bias, const float* __restrict__ res,
    void* __restrict__ Cout, float* __restrict__ zsum_g, const float* __restrict__ cinv_g,
    int M, int N, int K, long sA, long sB, long sC,
    long lda, long ldb, long ldc, float scale) {
  constexpr int MTI = MT / 32, NTI = NT / 32;   // 16x16 acc tiles per wave
  constexpr int SB = 64 * KU;                   // bytes per row k-slab
  constexpr int ABYT = MT * SB, BBYT = NT * SB;
  constexpr int BUFB = ABYT + BBYT;
  constexpr int AISS = MT * KU / 64, BISS = NT * KU / 64;
  constexpr int NL = AISS + BISS;
  constexpr int RPI = 16 / KU;                  // rows per staging issue
  constexpr int ES = (OUT_MODE == 0) ? 4 : 2;   // out element size
  constexpr int RS = NT * ES + 16;              // repack row stride (pad = 16B)
  constexpr int REPB = MT * RS;
  constexpr int SMEMB = (2 * BUFB > REPB) ? 2 * BUFB : REPB;
  constexpr int CPR = NT * ES / 16;             // 16B chunks per row
  constexpr int NCH = MT * CPR / 256;           // chunks per thread
  __shared__ char smem[SMEMB];
  const int tid = threadIdx.x;
  const int w = tid >> 6, l = tid & 63;
  const int wy = w >> 1, wx = w & 1;
  const int bz = blockIdx.z;
  int bx = blockIdx.x, by = blockIdx.y;
  if constexpr (SWIZ) {
    int l2 = by * gridDim.x + bx;
    int xcd = l2 & 7, s = l2 >> 3;
    by = xcd + (s & 3) * 8;
    bx = s >> 2;
  }
  const int m0 = by * MT, n0 = bx * NT;
  f32x4 acc[MTI][NTI] = {};

  // staging source column swizzle (bytes within the SB row-slab)
  int so;
  if constexpr (KU == 1) so = (((l & 3) - (l >> 2) - (l >> 4)) & 3) * 16;
  else                   so = (((l & 7) - (l >> 3)) & 7) * 16;
  const int lrow = (KU == 1) ? (l >> 2) : (l >> 3);
  const int arow = w * (MT / 4) + lrow;
  const int brow = w * (NT / 4) + lrow;
  const char* Ag = (const char*)A + ((size_t)bz * sA + (size_t)(m0 + arow) * lda) * 2 + so;
  const char* Bg = (const char*)B + ((size_t)bz * sB + (size_t)(n0 + brow) * ldb) * 2 + so;
  const size_t iadvA = (size_t)RPI * lda * 2;
  const size_t iadvB = (size_t)RPI * ldb * 2;
  const int woffA = w * (MT / 4) * SB;
  const int woffB = ABYT + w * (NT / 4) * SB;

  auto issue = [&](int buf) {
    char* base = smem + buf * BUFB;
#pragma unroll
    for (int i = 0; i < AISS; i++) gl_lds16(Ag + i * iadvA, base + woffA + i * 1024);
#pragma unroll
    for (int i = 0; i < BISS; i++) gl_lds16(Bg + i * iadvB, base + woffB + i * 1024);
    Ag += SB; Bg += SB;
  };

  // fragment-read column offsets (per KU half)
  const int x = l & 15;
  int qr0, qr1 = 0;
  if constexpr (KU == 1) {
    qr0 = (((l >> 4) + x + (x >> 2)) & 3) * 16;
  } else {
    qr0 = (((l >> 4) + (l & 7)) & 7) * 16;
    qr1 = (((l >> 4) + 4 + (l & 7)) & 7) * 16;
  }

  issue(0);
  const int T = K / (32 * KU);
  for (int t = 0; t < T; t++) {
    issue((t + 1) & 1);       // prefetch t+1 (last iter overshoots <=SB, lands in ws)
    wait_vmcnt<NL>();
    raw_barrier();
    const char* Asb = smem + (t & 1) * BUFB;
    const char* Bsb = Asb + ABYT;
#pragma unroll
    for (int h = 0; h < KU; h++) {
      const int q = (h == 0) ? qr0 : qr1;
      bf16x8 af[MTI], bfr[NTI];
#pragma unroll
      for (int mt = 0; mt < MTI; mt++)
        af[mt] = *(const bf16x8*)(Asb + (wy * (MT / 2) + mt * 16 + x) * SB + q);
#pragma unroll
      for (int nt = 0; nt < NTI; nt++)
        bfr[nt] = *(const bf16x8*)(Bsb + (wx * (NT / 2) + nt * 16 + x) * SB + q);
#pragma unroll
      for (int mt = 0; mt < MTI; mt++)
#pragma unroll
        for (int nt = 0; nt < NTI; nt++)
          acc[mt][nt] = __builtin_amdgcn_mfma_f32_16x16x32_bf16(af[mt], bfr[nt], acc[mt][nt], 0, 0, 0);
    }
    raw_barrier();            // all waves done reading buf before t+2 overwrites
  }

  // ---- epilogue: value phase -> LDS repack -> coalesced store phase ----
  drain_vm();      // stray tile-T prefetch landed
  raw_barrier();
  const size_t cbase = (size_t)bz * sC;
#pragma unroll
  for (int mt = 0; mt < MTI; mt++) {
#pragma unroll
    for (int r = 0; r < 4; r++) {
      const int row = wy * (MT / 2) + mt * 16 + (l >> 4) * 4 + r;  // block-local m
      float bvm = (BIAS_MODE == 1) ? bias[m0 + row] : 0.f;
      float cm = 1.f;
      if constexpr (SCALEM) cm = cinv_g[(size_t)bz * M + m0 + row];
      float z = 0.f;
#pragma unroll
      for (int nt = 0; nt < NTI; nt++) {
        const int nl = wx * (NT / 2) + nt * 16 + x;
        float v = acc[mt][nt][r] * scale + bvm;
        if (BIAS_MODE == 2) v += bias[n0 + nl];
        if constexpr (EXPZ) { v = __expf(v); z += v; }
        if constexpr (SCALEM) v *= cm;
        if (OUT_MODE == 0) *(float*)(smem + row * RS + nl * 4) = v;
        else *(short*)(smem + row * RS + nl * 2) = bf16_bits(v);
      }
      if constexpr (EXPZ) {
        z += __shfl_xor(z, 1); z += __shfl_xor(z, 2);
        z += __shfl_xor(z, 4); z += __shfl_xor(z, 8);
        if (x == 0)
          zsum_g[((size_t)bz * 64 + bx * 2 + wx) * M + m0 + row] = z;
      }
    }
  }
  __syncthreads();
#pragma unroll
  for (int i = 0; i < NCH; i++) {
    const int g = i * 256 + tid;
    const int row = g / CPR;
    const int off = (g % CPR) * 16;
    char* dst = (char*)Cout + (cbase + (size_t)(m0 + row) * ldc + n0) * ES + off;
    if (OUT_MODE == 0) {
      float4 d = *(float4*)(smem + row * RS + off);
      if constexpr (HAS_RES) {
        float4 rv = *(const float4*)((const char*)res + (cbase + (size_t)(m0 + row) * ldc + n0) * 4 + off);
        d.x += rv.x; d.y += rv.y; d.z += rv.z; d.w += rv.w;
      }
      *(float4*)dst = d;
    } else {
      int4 d = *(int4*)(smem + row * RS + off);
      *(int4*)dst = d;
    }
  }
}

// ---------------- Z combine: cinv[b][j] = 1 / sum_p zsum[b][p][j] ----------------
__global__ __launch_bounds__(256) void zcomb(const float* __restrict__ zsum,
                                             float* __restrict__ cinv) {
  int idx = blockIdx.x * 256 + threadIdx.x;  // b*NDIM + j, 8192 total
  int b = idx >> 12, j = idx & (NDIM - 1);
  float s = 0.f;
#pragma unroll 8
  for (int p = 0; p < 64; p++) s += zsum[((size_t)b * 64 + p) * NDIM + j];
  cinv[idx] = 1.0f / s;
}

extern "C" void kernel_launch(void* const* d_in, const int* in_sizes, int n_in,
                              void* d_out, int out_size, void* d_ws, size_t ws_size,
                              hipStream_t stream) {
  const float* x      = (const float*)d_in[0];
  const float* norm_w = (const float*)d_in[1];
  const float* norm_b = (const float*)d_in[2];
  const float* wq = (const float*)d_in[3];
  const float* bq = (const float*)d_in[4];
  const float* wk = (const float*)d_in[5];
  const float* bk = (const float*)d_in[6];
  const float* wv = (const float*)d_in[7];
  const float* bv = (const float*)d_in[8];
  const float* wp = (const float*)d_in[9];
  const float* bp = (const float*)d_in[10];
  float* out = (float*)d_out;

  const long CN = (long)CDIM * NDIM;       // 2M elems
  const long NN = (long)NDIM * NDIM;       // 16M elems
  const long QKN = (long)NDIM * 1024;      // merged q|k, [N,1024]
  char* p = (char*)d_ws;
  auto carve = [&](size_t bytes) { char* r = p; p += (bytes + 255) & ~(size_t)255; return r; };
  __hip_bfloat16* h_t  = (__hip_bfloat16*)carve(BATCH * CN * 2);   // [B,N,C]
  __hip_bfloat16* wb   = (__hip_bfloat16*)carve(4 * 512 * 512 * 2);
  __hip_bfloat16* qk_t = (__hip_bfloat16*)carve(BATCH * QKN * 2);  // [B,N,1024]: q 0-511, k 512-1023
  __hip_bfloat16* vb   = (__hip_bfloat16*)carve(BATCH * CN * 2);   // [B,C,N]
  __hip_bfloat16* ht2  = (__hip_bfloat16*)carve(BATCH * CN * 2);   // [B,N,C]
  __hip_bfloat16* St   = (__hip_bfloat16*)carve(BATCH * NN * 2);   // [B,N,N] E^T = exp(S^T)
  float* zsum  = (float*)carve((size_t)BATCH * 64 * NDIM * 4);     // slack for stray prefetch
  float* cinv  = (float*)carve(BATCH * NDIM * 4);
  float* bqk   = (float*)carve(1024 * 4);
  float2* stats = (float2*)carve(BATCH * NGROUPS * sizeof(float2));
  float2* gnpart = (float2*)carve(1024 * sizeof(float2));
  __hip_bfloat16* wbv = wb + 524288;
  __hip_bfloat16* wbp = wb + 786432;

  const float scale = 0.044194173824159216f;  // 512^-0.5

  gn_stats_p1<<<dim3(1024), 256, 0, stream>>>(x, gnpart);
  gn_stats_p2<<<dim3(1), 64, 0, stream>>>(gnpart, stats);
  gn_apply_t<<<dim3(NDIM / 64, CDIM / 64, BATCH), 256, 0, stream>>>(x, stats, norm_w, norm_b, h_t);
  cvt_w<<<dim3(1024), 256, 0, stream>>>(wq, wk, wv, wp, wb, bq, bk, bqk);

  // qk_t[n][0..1023] = h_t @ [wq;wk]^T + [bq;bk]   (SWIZ; BK=64; 3/CU)
  mfma_gemm_nt<128, 64, 2, 2, false, 1, false, false, true, 3><<<dim3(16, 32, BATCH), 256, 0, stream>>>(
      h_t, wb, bqk, nullptr, qk_t, nullptr, nullptr,
      NDIM, 1024, CDIM, CN, 0, QKN, CDIM, CDIM, 1024, 1.0f);
  // v = wv @ h_t^T + bv -> [C, N]   (BK=64; 3/CU)
  mfma_gemm_nt<64, 128, 2, 1, false, 1, false, false, false, 3><<<dim3(32, 8, BATCH), 256, 0, stream>>>(
      wbv, h_t, bv, nullptr, vb, nullptr, nullptr,
      CDIM, NDIM, CDIM, 0, CN, CN, CDIM, CDIM, NDIM, 1.0f);
  // E^T = exp(k_t @ q_t^T * scale) -> [N, N] bf16, fused partial Z row-sums
  // 128x128, BK=32, 4 blocks/CU (16 waves/CU; VGPR headroom is large)
  mfma_gemm_nt<128, 128, 1, 0, false, 1, true, false, false, 4><<<dim3(32, 32, BATCH), 256, 0, stream>>>(
      qk_t + 512, qk_t, nullptr, nullptr, St, zsum, nullptr,
      NDIM, NDIM, CDIM, QKN, QKN, NN, 1024, 1024, NDIM, scale);
  zcomb<<<dim3(32), 256, 0, stream>>>(zsum, cinv);
  // ht2 = diag(cinv) (E^T @ v^T) -> [N, C]   (SWIZ; BK=64; 3/CU)
  mfma_gemm_nt<128, 64, 2, 0, false, 1, false, true, true, 3><<<dim3(8, 32, BATCH), 256, 0, stream>>>(
      St, vb, nullptr, nullptr, ht2, nullptr, cinv,
      NDIM, CDIM, NDIM, NN, CN, CN, NDIM, NDIM, CDIM, 1.0f);
  // out = wp @ ht2^T + bp + x -> [C, N] fp32 (residual fused in store phase; 3/CU)
  mfma_gemm_nt<64, 128, 2, 1, true, 0, false, false, false, 3><<<dim3(32, 8, BATCH), 256, 0, stream>>>(
      wbp, ht2, bp, x, out, nullptr, nullptr,
      CDIM, NDIM, CDIM, 0, CN, CN, CDIM, CDIM, NDIM, 1.0f);
}